// Round 7
// baseline (199.169 us; speedup 1.0000x reference)
//
#include <hip/hip_runtime.h>
#include <math.h>

#define NN 4096
#define NFEAT 512
#define NHID 60
#define NCLASS 4
#define CAP 96      // per-row nnz capacity (mean ~8.2, statistical max ~22)
#define GSTRIDE 64  // padded hidden-state row stride
#define QCAP 256    // per-block nonzero-element queue (mean ~16, 16x headroom)
#define GECAP 65536 // global edge-list capacity (expected ~33.5K)
#define XWBLK (NN / 4)                // 1024 xw blocks (overlap with stream)
#define SCANBLK (NN * NN / 4 / 2048)  // 2048 stream blocks

// ---- process one edge element e = i*4096+j (adj value is exactly 1.0f) ----
__device__ __forceinline__ void scan_elem(int e,
                                          const float* __restrict__ P,
                                          float* __restrict__ dcol,
                                          int* __restrict__ cnt,
                                          int* __restrict__ cols,
                                          float* __restrict__ vals) {
    const int i = e >> 12;
    const int j = e & (NN - 1);
    const int hi = i > j ? i : j;
    const int lo = i > j ? j : i;
    const float pv = P[((hi * (hi + 1)) >> 1) + lo];
    const float s = 1.f / (1.f + __expf(-pv));      // sigmoid(P) * 1.0
    atomicAdd(&dcol[j], s);
    const int pos = atomicAdd(&cnt[i], 1);
    if (pos < CAP) { cols[i * CAP + pos] = j; vals[i * CAP + pos] = s; }
}

// ---- dispatch 1: xw blocks [0,1024) || pure-stream blocks [1024,3072) -----
// Stream half touches NO scattered data and does NO global atomics except one
// per-block space reservation: read 8 uint4/thread, integer-test, LDS-queue
// nonzero element indices, coalesced copy to the global edge list.
__global__ __launch_bounds__(256) void k_stream_xw(const float* __restrict__ x,
                                                   const float* __restrict__ adj,
                                                   const float* __restrict__ P,
                                                   const float* __restrict__ W1,
                                                   float* __restrict__ dcol,
                                                   int* __restrict__ cnt,
                                                   int* __restrict__ cols,
                                                   float* __restrict__ vals,
                                                   int* __restrict__ nedge,
                                                   int* __restrict__ gedges,
                                                   float* __restrict__ g1) {
    __shared__ float part[1024];
    __shared__ int q[QCAP];
    __shared__ int qn, qbase;
    const int tid = threadIdx.x;

    if (blockIdx.x >= XWBLK) {
        // ---- pure stream + compact -----------------------------------
        if (tid == 0) qn = 0;
        __syncthreads();
        const int base = (blockIdx.x - XWBLK) * 2048 + tid;   // float4 index
        const uint4* adj4 = (const uint4*)adj;
        uint4 a[8];
        #pragma unroll
        for (int u = 0; u < 8; ++u) a[u] = adj4[base + u * 256];  // 8 in flight
        #pragma unroll
        for (int u = 0; u < 8; ++u) {
            const uint4 v = a[u];
            if (v.x | v.y | v.z | v.w) {                      // adj is 0.0f/1.0f
                const int e0 = (base + u * 256) * 4;
                const unsigned m[4] = {v.x, v.y, v.z, v.w};
                #pragma unroll
                for (int qq = 0; qq < 4; ++qq) {
                    if (m[qq]) {
                        const int p = atomicAdd(&qn, 1);      // LDS atomic
                        if (p < QCAP) q[p] = e0 + qq;
                        else scan_elem(e0 + qq, P, dcol, cnt, cols, vals);
                    }
                }
            }
        }
        __syncthreads();
        const int n = min(qn, QCAP);
        if (tid == 0) qbase = atomicAdd(nedge, n);            // 1 global atomic
        __syncthreads();
        for (int t = tid; t < n; t += 256) {                  // coalesced copy
            const int dst = qbase + t;
            if (dst < GECAP) gedges[dst] = q[t];
            else scan_elem(q[t], P, dcol, cnt, cols, vals);   // never expected
        }
        return;
    }

    // ---- x @ W1: 4 rows/block, K split over 4 waves -------------------
    const int w = tid >> 6, lane = tid & 63;
    const int c = lane < NHID ? lane : 0;
    const int row0 = blockIdx.x * 4;
    const int k0 = w * (NFEAT / 4);
    const float* x0 = x + (row0 + 0) * NFEAT;
    const float* x1 = x + (row0 + 1) * NFEAT;
    const float* x2 = x + (row0 + 2) * NFEAT;
    const float* x3 = x + (row0 + 3) * NFEAT;
    float a0 = 0.f, a1 = 0.f, a2 = 0.f, a3 = 0.f;
    for (int k = k0; k < k0 + NFEAT / 4; k += 4) {
        const float4 xv0 = *(const float4*)(x0 + k);   // wave-uniform 16B
        const float4 xv1 = *(const float4*)(x1 + k);
        const float4 xv2 = *(const float4*)(x2 + k);
        const float4 xv3 = *(const float4*)(x3 + k);
        const float w0 = W1[(k + 0) * NHID + c];       // lane-varying, L2-hot
        const float w1 = W1[(k + 1) * NHID + c];
        const float w2 = W1[(k + 2) * NHID + c];
        const float w3 = W1[(k + 3) * NHID + c];
        a0 = fmaf(xv0.x, w0, fmaf(xv0.y, w1, fmaf(xv0.z, w2, fmaf(xv0.w, w3, a0))));
        a1 = fmaf(xv1.x, w0, fmaf(xv1.y, w1, fmaf(xv1.z, w2, fmaf(xv1.w, w3, a1))));
        a2 = fmaf(xv2.x, w0, fmaf(xv2.y, w1, fmaf(xv2.z, w2, fmaf(xv2.w, w3, a2))));
        a3 = fmaf(xv3.x, w0, fmaf(xv3.y, w1, fmaf(xv3.z, w2, fmaf(xv3.w, w3, a3))));
    }
    part[(w * 4 + 0) * 64 + lane] = a0;
    part[(w * 4 + 1) * 64 + lane] = a1;
    part[(w * 4 + 2) * 64 + lane] = a2;
    part[(w * 4 + 3) * 64 + lane] = a3;
    __syncthreads();
    // wave w reduces row w across the 4 K-slices
    const float o = part[(0 * 4 + w) * 64 + lane] + part[(1 * 4 + w) * 64 + lane]
                  + part[(2 * 4 + w) * 64 + lane] + part[(3 * 4 + w) * 64 + lane];
    g1[(row0 + w) * GSTRIDE + lane] = (lane < NHID) ? o : 0.f;
}

// ---- dispatch 2: one edge per thread — all chains concurrent --------------
__global__ __launch_bounds__(256) void k_edges(const float* __restrict__ P,
                                               float* __restrict__ dcol,
                                               int* __restrict__ cnt,
                                               int* __restrict__ cols,
                                               float* __restrict__ vals,
                                               const int* __restrict__ nedge,
                                               const int* __restrict__ gedges) {
    const int t = blockIdx.x * 256 + threadIdx.x;
    const int n = min(*nedge, GECAP);
    if (t < n) scan_elem(gedges[t], P, dcol, cnt, cols, vals);
}

// ---- spmm edge accumulation, 4-batched for MLP ----------------------------
__device__ __forceinline__ float spmm_row(const float* __restrict__ gin,
                                          const float* __restrict__ dcol,
                                          const int* __restrict__ cnt,
                                          const int* __restrict__ cols,
                                          const float* __restrict__ vals,
                                          int i, int lane, float di) {
    const int nn = min(cnt[i], CAP);
    float acc = gin[i * GSTRIDE + lane] * di;   // self-loop term
    const int4*   c4 = (const int4*)(cols + i * CAP);
    const float4* v4 = (const float4*)(vals + i * CAP);
    int e = 0;
    for (; e + 4 <= nn; e += 4) {
        const int4   jj = c4[e >> 2];
        const float4 vv = v4[e >> 2];
        const float f0 = vv.x * rsqrtf(1.f + dcol[jj.x]);
        const float f1 = vv.y * rsqrtf(1.f + dcol[jj.y]);
        const float f2 = vv.z * rsqrtf(1.f + dcol[jj.z]);
        const float f3 = vv.w * rsqrtf(1.f + dcol[jj.w]);
        const float g0 = gin[jj.x * GSTRIDE + lane];
        const float g1 = gin[jj.y * GSTRIDE + lane];
        const float g2 = gin[jj.z * GSTRIDE + lane];
        const float g3 = gin[jj.w * GSTRIDE + lane];
        acc = fmaf(f0, g0, fmaf(f1, g1, fmaf(f2, g2, fmaf(f3, g3, acc))));
    }
    for (; e < nn; ++e) {
        const int j = cols[i * CAP + e];
        const float f = vals[i * CAP + e] * rsqrtf(1.f + dcol[j]);
        acc = fmaf(f, gin[j * GSTRIDE + lane], acc);
    }
    return acc * di;
}

// ---- h = relu(spmm(gin)+bias); gout = h @ W. 4 rows/block, W in LDS. ------
__global__ __launch_bounds__(256) void k_layer(const float* __restrict__ gin,
                                               float* __restrict__ gout,
                                               const float* __restrict__ dcol,
                                               const int* __restrict__ cnt,
                                               const int* __restrict__ cols,
                                               const float* __restrict__ vals,
                                               const float* __restrict__ bias,
                                               const float* __restrict__ W) {
    __shared__ float Ws[NHID * NHID];   // 14.4 KB, loaded once per block
    __shared__ float hs[256];
    const int tid = threadIdx.x;
    for (int t = tid; t < NHID * NHID; t += 256) Ws[t] = W[t];
    const int w = tid >> 6, lane = tid & 63;
    const int i = blockIdx.x * 4 + w;               // one row per wave
    const float di = rsqrtf(1.f + dcol[i]);
    const float acc = spmm_row(gin, dcol, cnt, cols, vals, i, lane, di);
    hs[w * 64 + lane] = (lane < NHID) ? fmaxf(acc + bias[lane], 0.f) : 0.f;
    __syncthreads();                                // covers Ws + hs stores
    const int c = lane < NHID ? lane : 0;
    float o = 0.f;
    #pragma unroll 6
    for (int k = 0; k < NHID; ++k)
        o = fmaf(hs[w * 64 + k], Ws[k * NHID + c], o);  // broadcast + 2/bank (free)
    gout[i * GSTRIDE + lane] = (lane < NHID) ? o : 0.f;
}

// ---- h3 = spmm+b3; logits = h3@lin_w+lin_b; log_softmax. 4 rows/block. ----
__global__ __launch_bounds__(256) void k_final(const float* __restrict__ gin,
                                               float* __restrict__ out,
                                               const float* __restrict__ dcol,
                                               const int* __restrict__ cnt,
                                               const int* __restrict__ cols,
                                               const float* __restrict__ vals,
                                               const float* __restrict__ b3,
                                               const float* __restrict__ lw,
                                               const float* __restrict__ lb) {
    __shared__ float lws[NHID * NCLASS];  // 240 floats
    __shared__ float hs[256];
    const int tid = threadIdx.x;
    for (int t = tid; t < NHID * NCLASS; t += 256) lws[t] = lw[t];
    const int w = tid >> 6, lane = tid & 63;
    const int i = blockIdx.x * 4 + w;
    const float di = rsqrtf(1.f + dcol[i]);
    const float acc = spmm_row(gin, dcol, cnt, cols, vals, i, lane, di);
    hs[w * 64 + lane] = (lane < NHID) ? acc + b3[lane] : 0.f;
    __syncthreads();
    if (lane < NCLASS) {
        float o = lb[lane];
        #pragma unroll 4
        for (int k = 0; k < NHID; ++k)
            o = fmaf(hs[w * 64 + k], lws[k * NCLASS + lane], o);
        float m = fmaxf(o, __shfl_xor(o, 1));
        m = fmaxf(m, __shfl_xor(m, 2));
        const float ex = __expf(o - m);
        float ss = ex + __shfl_xor(ex, 1);
        ss += __shfl_xor(ss, 2);
        out[i * NCLASS + lane] = o - m - __logf(ss);
    }
}

extern "C" void kernel_launch(void* const* d_in, const int* in_sizes, int n_in,
                              void* d_out, int out_size, void* d_ws, size_t ws_size,
                              hipStream_t stream) {
    const float* x   = (const float*)d_in[0];   // 4096 x 512
    const float* adj = (const float*)d_in[1];   // 4096 x 4096
    const float* P   = (const float*)d_in[2];   // 8390656
    const float* W1  = (const float*)d_in[3];   // 512 x 60
    const float* b1  = (const float*)d_in[4];
    const float* W2  = (const float*)d_in[5];   // 60 x 60
    const float* b2  = (const float*)d_in[6];
    const float* W3  = (const float*)d_in[7];   // 60 x 60
    const float* b3  = (const float*)d_in[8];
    const float* lw  = (const float*)d_in[9];   // 60 x 4
    const float* lb  = (const float*)d_in[10];
    float* out = (float*)d_out;                 // 4096 x 4

    char* ws = (char*)d_ws;
    float* dcol   = (float*)(ws);               // 16 KiB (zeroed)
    int*   cnt    = (int*)(ws + 16384);         // 16 KiB (zeroed)
    int*   nedge  = (int*)(ws + 32768);         // 4 B    (zeroed)
    int*   gedges = (int*)(ws + 33024);         // 256 KiB edge list
    int*   cols   = (int*)(ws + 295168);                          // 1.5 MiB
    float* vals   = (float*)(ws + 295168 + 1572864);              // 1.5 MiB
    float* bufA   = (float*)(ws + 295168 + 2 * 1572864);          // 1 MiB
    float* bufB   = (float*)(ws + 295168 + 2 * 1572864 + 1048576);// 1 MiB

    hipMemsetAsync(ws, 0, 33024, stream);       // zero dcol + cnt + nedge

    k_stream_xw<<<XWBLK + SCANBLK, 256, 0, stream>>>(x, adj, P, W1, dcol, cnt,
                                                     cols, vals, nedge, gedges, bufA);
    k_edges<<<GECAP / 256, 256, 0, stream>>>(P, dcol, cnt, cols, vals, nedge, gedges);
    k_layer<<<NN / 4, 256, 0, stream>>>(bufA, bufB, dcol, cnt, cols, vals, b1, W2);
    k_layer<<<NN / 4, 256, 0, stream>>>(bufB, bufA, dcol, cnt, cols, vals, b2, W3);
    k_final<<<NN / 4, 256, 0, stream>>>(bufA, out, dcol, cnt, cols, vals, b3, lw, lb);
}

// Round 8
// 189.253 us; speedup vs baseline: 1.0524x; 1.0524x over previous
//
#include <hip/hip_runtime.h>
#include <math.h>

#define NN 4096
#define NFEAT 512
#define NHID 60
#define NCLASS 4
#define CAP 96      // per-row nnz capacity (mean ~8.2, statistical max ~22)
#define GSTRIDE 64  // padded hidden-state row stride
#define QCAP 128    // per-wave nonzero-float4 queue (mean ~16, 8x headroom)
#define SCANBLK (NN * NN / 4 / 2048)  // 2048 scan blocks -- FIRST in grid
#define XWBLK (NN / 4)                // 1024 xw blocks (fill the scan's drain)

// ---- process one nonzero float4 of the adjacency --------------------------
__device__ __forceinline__ void scan_f4(const float4 av4, int f4idx,
                                        const float* __restrict__ P,
                                        float* __restrict__ dcol,
                                        int* __restrict__ cnt,
                                        int* __restrict__ cols,
                                        float* __restrict__ vals) {
    const float av[4] = {av4.x, av4.y, av4.z, av4.w};
    const int e0 = f4idx * 4;
    #pragma unroll
    for (int q = 0; q < 4; ++q) {
        if (av[q] != 0.f) {
            const int e = e0 + q;
            const int i = e >> 12;
            const int j = e & (NN - 1);
            const int hi = i > j ? i : j;
            const int lo = i > j ? j : i;
            const float pv = P[((hi * (hi + 1)) >> 1) + lo];
            const float s = av[q] / (1.f + __expf(-pv));   // sigmoid(P) * adj
            atomicAdd(&dcol[j], s);
            const int pos = atomicAdd(&cnt[i], 1);
            if (pos < CAP) { cols[i * CAP + pos] = j; vals[i * CAP + pos] = s; }
        }
    }
}

// ---- merged dispatch: scan blocks [0,2048) FIRST (stream starts at t=0), --
// xw blocks [2048,3072) launch into the scan's drain and overlap its tail.
__global__ __launch_bounds__(256) void k_scan_xw(const float* __restrict__ x,
                                                 const float* __restrict__ adj,
                                                 const float* __restrict__ P,
                                                 const float* __restrict__ W1,
                                                 float* __restrict__ dcol,
                                                 int* __restrict__ cnt,
                                                 int* __restrict__ cols,
                                                 float* __restrict__ vals,
                                                 float* __restrict__ g1) {
    __shared__ float xs[4 * NFEAT];   // 8 KB x-tile (xw path)
    __shared__ int wq[4][QCAP];       // scan path queues
    __shared__ int wq_n[4];
    const int tid = threadIdx.x;
    const int w = tid >> 6, lane = tid & 63;

    if (blockIdx.x < SCANBLK) {
        // ---- scan: stream-compact then lane-parallel process ----------
        if (tid < 4) wq_n[tid] = 0;
        __syncthreads();
        const int base = blockIdx.x * 2048 + tid;             // float4 index
        const uint4* adj4 = (const uint4*)adj;
        uint4 a[8];
        #pragma unroll
        for (int u = 0; u < 8; ++u) a[u] = adj4[base + u * 256];  // 8 in flight
        #pragma unroll
        for (int u = 0; u < 8; ++u) {
            if (a[u].x | a[u].y | a[u].z | a[u].w) {          // adj is 0.0f/1.0f
                const int p = atomicAdd(&wq_n[w], 1);         // LDS atomic, cheap
                if (p < QCAP) wq[w][p] = base + u * 256;
                else {                                        // never expected
                    const uint4 v = a[u];
                    const float4 f = make_float4(__uint_as_float(v.x), __uint_as_float(v.y),
                                                 __uint_as_float(v.z), __uint_as_float(v.w));
                    scan_f4(f, base + u * 256, P, dcol, cnt, cols, vals);
                }
            }
        }
        __syncthreads();                                      // pushes visible
        const int n = min(wq_n[w], QCAP);
        for (int l = lane; l < n; l += 64) {                  // one entry per lane
            const int idx = wq[w][l];
            scan_f4(((const float4*)adj)[idx], idx, P, dcol, cnt, cols, vals);
        }
        return;
    }

    // ---- x @ W1: 4 rows/block, x staged in LDS via coalesced loads, ----
    // one row per wave, lane-parallel W1 loads (240 B/instr, L2-hot).
    const int row0 = (blockIdx.x - SCANBLK) * 4;
    const float4* x4 = (const float4*)x + row0 * (NFEAT / 4); // 512 float4s
    float4* xs4 = (float4*)xs;
    xs4[tid]       = x4[tid];                                 // 2 coalesced
    xs4[tid + 256] = x4[tid + 256];                           // 16B/lane loads
    __syncthreads();
    const int c = lane < NHID ? lane : 0;
    const float* xrow = xs + w * NFEAT;                       // wave's row
    float a0 = 0.f, a1 = 0.f, a2 = 0.f, a3 = 0.f;
    #pragma unroll 4
    for (int k = 0; k < NFEAT; k += 4) {                      // 16 loads in flight
        a0 = fmaf(xrow[k + 0], W1[(k + 0) * NHID + c], a0);   // xrow: LDS broadcast
        a1 = fmaf(xrow[k + 1], W1[(k + 1) * NHID + c], a1);
        a2 = fmaf(xrow[k + 2], W1[(k + 2) * NHID + c], a2);
        a3 = fmaf(xrow[k + 3], W1[(k + 3) * NHID + c], a3);
    }
    g1[(row0 + w) * GSTRIDE + lane] = (lane < NHID) ? (a0 + a1) + (a2 + a3) : 0.f;
}

// ---- spmm edge accumulation, 4-batched for MLP ----------------------------
__device__ __forceinline__ float spmm_row(const float* __restrict__ gin,
                                          const float* __restrict__ dcol,
                                          const int* __restrict__ cnt,
                                          const int* __restrict__ cols,
                                          const float* __restrict__ vals,
                                          int i, int lane, float di) {
    const int nn = min(cnt[i], CAP);
    float acc = gin[i * GSTRIDE + lane] * di;   // self-loop term
    const int4*   c4 = (const int4*)(cols + i * CAP);
    const float4* v4 = (const float4*)(vals + i * CAP);
    int e = 0;
    for (; e + 4 <= nn; e += 4) {
        const int4   jj = c4[e >> 2];
        const float4 vv = v4[e >> 2];
        const float f0 = vv.x * rsqrtf(1.f + dcol[jj.x]);
        const float f1 = vv.y * rsqrtf(1.f + dcol[jj.y]);
        const float f2 = vv.z * rsqrtf(1.f + dcol[jj.z]);
        const float f3 = vv.w * rsqrtf(1.f + dcol[jj.w]);
        const float g0 = gin[jj.x * GSTRIDE + lane];
        const float g1 = gin[jj.y * GSTRIDE + lane];
        const float g2 = gin[jj.z * GSTRIDE + lane];
        const float g3 = gin[jj.w * GSTRIDE + lane];
        acc = fmaf(f0, g0, fmaf(f1, g1, fmaf(f2, g2, fmaf(f3, g3, acc))));
    }
    for (; e < nn; ++e) {
        const int j = cols[i * CAP + e];
        const float f = vals[i * CAP + e] * rsqrtf(1.f + dcol[j]);
        acc = fmaf(f, gin[j * GSTRIDE + lane], acc);
    }
    return acc * di;
}

// ---- h = relu(spmm(gin)+bias); gout = h @ W. 4 rows/block, W in LDS. ------
__global__ __launch_bounds__(256) void k_layer(const float* __restrict__ gin,
                                               float* __restrict__ gout,
                                               const float* __restrict__ dcol,
                                               const int* __restrict__ cnt,
                                               const int* __restrict__ cols,
                                               const float* __restrict__ vals,
                                               const float* __restrict__ bias,
                                               const float* __restrict__ W) {
    __shared__ float Ws[NHID * NHID];   // 14.4 KB, loaded once per block
    __shared__ float hs[256];
    const int tid = threadIdx.x;
    for (int t = tid; t < NHID * NHID; t += 256) Ws[t] = W[t];
    const int w = tid >> 6, lane = tid & 63;
    const int i = blockIdx.x * 4 + w;               // one row per wave
    const float di = rsqrtf(1.f + dcol[i]);
    const float acc = spmm_row(gin, dcol, cnt, cols, vals, i, lane, di);
    hs[w * 64 + lane] = (lane < NHID) ? fmaxf(acc + bias[lane], 0.f) : 0.f;
    __syncthreads();                                // covers Ws + hs stores
    const int c = lane < NHID ? lane : 0;
    float o = 0.f;
    #pragma unroll 6
    for (int k = 0; k < NHID; ++k)
        o = fmaf(hs[w * 64 + k], Ws[k * NHID + c], o);  // broadcast + 2/bank (free)
    gout[i * GSTRIDE + lane] = (lane < NHID) ? o : 0.f;
}

// ---- h3 = spmm+b3; logits = h3@lin_w+lin_b; log_softmax. 4 rows/block. ----
__global__ __launch_bounds__(256) void k_final(const float* __restrict__ gin,
                                               float* __restrict__ out,
                                               const float* __restrict__ dcol,
                                               const int* __restrict__ cnt,
                                               const int* __restrict__ cols,
                                               const float* __restrict__ vals,
                                               const float* __restrict__ b3,
                                               const float* __restrict__ lw,
                                               const float* __restrict__ lb) {
    __shared__ float lws[NHID * NCLASS];  // 240 floats
    __shared__ float hs[256];
    const int tid = threadIdx.x;
    for (int t = tid; t < NHID * NCLASS; t += 256) lws[t] = lw[t];
    const int w = tid >> 6, lane = tid & 63;
    const int i = blockIdx.x * 4 + w;
    const float di = rsqrtf(1.f + dcol[i]);
    const float acc = spmm_row(gin, dcol, cnt, cols, vals, i, lane, di);
    hs[w * 64 + lane] = (lane < NHID) ? acc + b3[lane] : 0.f;
    __syncthreads();
    if (lane < NCLASS) {
        float o = lb[lane];
        #pragma unroll 4
        for (int k = 0; k < NHID; ++k)
            o = fmaf(hs[w * 64 + k], lws[k * NCLASS + lane], o);
        float m = fmaxf(o, __shfl_xor(o, 1));
        m = fmaxf(m, __shfl_xor(m, 2));
        const float ex = __expf(o - m);
        float ss = ex + __shfl_xor(ex, 1);
        ss += __shfl_xor(ss, 2);
        out[i * NCLASS + lane] = o - m - __logf(ss);
    }
}

extern "C" void kernel_launch(void* const* d_in, const int* in_sizes, int n_in,
                              void* d_out, int out_size, void* d_ws, size_t ws_size,
                              hipStream_t stream) {
    const float* x   = (const float*)d_in[0];   // 4096 x 512
    const float* adj = (const float*)d_in[1];   // 4096 x 4096
    const float* P   = (const float*)d_in[2];   // 8390656
    const float* W1  = (const float*)d_in[3];   // 512 x 60
    const float* b1  = (const float*)d_in[4];
    const float* W2  = (const float*)d_in[5];   // 60 x 60
    const float* b2  = (const float*)d_in[6];
    const float* W3  = (const float*)d_in[7];   // 60 x 60
    const float* b3  = (const float*)d_in[8];
    const float* lw  = (const float*)d_in[9];   // 60 x 4
    const float* lb  = (const float*)d_in[10];
    float* out = (float*)d_out;                 // 4096 x 4

    char* ws = (char*)d_ws;
    float* dcol = (float*)(ws);                 // 16 KiB (zeroed)
    int*   cnt  = (int*)(ws + 16384);           // 16 KiB (zeroed)
    int*   cols = (int*)(ws + 32768);                           // 1.5 MiB
    float* vals = (float*)(ws + 32768 + 1572864);               // 1.5 MiB
    float* bufA = (float*)(ws + 32768 + 2 * 1572864);           // 1 MiB
    float* bufB = (float*)(ws + 32768 + 2 * 1572864 + 1048576); // 1 MiB

    hipMemsetAsync(ws, 0, 32768, stream);       // zero dcol + cnt

    k_scan_xw<<<SCANBLK + XWBLK, 256, 0, stream>>>(x, adj, P, W1,
                                                   dcol, cnt, cols, vals, bufA);
    k_layer<<<NN / 4, 256, 0, stream>>>(bufA, bufB, dcol, cnt, cols, vals, b1, W2);
    k_layer<<<NN / 4, 256, 0, stream>>>(bufB, bufA, dcol, cnt, cols, vals, b2, W3);
    k_final<<<NN / 4, 256, 0, stream>>>(bufA, out, dcol, cnt, cols, vals, b3, lw, lb);
}